// Round 1
// baseline (749.493 us; speedup 1.0000x reference)
//
#include <hip/hip_runtime.h>

#define D 128

// ---------------- CSR build ----------------

__global__ void k_count(const int* __restrict__ dst, int* __restrict__ deg, int E) {
  int e = blockIdx.x * blockDim.x + threadIdx.x;
  if (e < E) atomicAdd(&deg[dst[e]], 1);
}

__global__ void k_scan_intra(const int* __restrict__ deg, int* __restrict__ row_off,
                             int* __restrict__ partials, int N) {
  __shared__ int s[256];
  int t = threadIdx.x;
  int i = blockIdx.x * 256 + t;
  int v = (i < N) ? deg[i] : 0;
  s[t] = v;
  __syncthreads();
  for (int off = 1; off < 256; off <<= 1) {
    int x = 0;
    if (t >= off) x = s[t - off];
    __syncthreads();
    if (t >= off) s[t] += x;
    __syncthreads();
  }
  if (i < N) row_off[i] = s[t] - v;            // exclusive within block
  if (t == 255) partials[blockIdx.x] = s[255]; // block total
}

__global__ void k_scan_partials(int* partials, int NB) {
  __shared__ int s[256];
  __shared__ int carry;
  int t = threadIdx.x;
  if (t == 0) carry = 0;
  __syncthreads();
  for (int base = 0; base < NB; base += 256) {
    int i = base + t;
    int v = (i < NB) ? partials[i] : 0;
    s[t] = v;
    __syncthreads();
    for (int off = 1; off < 256; off <<= 1) {
      int x = 0;
      if (t >= off) x = s[t - off];
      __syncthreads();
      if (t >= off) s[t] += x;
      __syncthreads();
    }
    if (i < NB) partials[i] = carry + s[t] - v; // exclusive, with carry
    __syncthreads();
    if (t == 255) carry += s[255];
    __syncthreads();
  }
}

__global__ void k_finalize(int* __restrict__ row_off, const int* __restrict__ partials,
                           const int* __restrict__ deg, float* __restrict__ inv_deg,
                           int N, int E) {
  int i = blockIdx.x * 256 + threadIdx.x;
  if (i < N) {
    row_off[i] += partials[blockIdx.x];
    inv_deg[i] = 1.0f / fmaxf((float)deg[i], 1.0f);
  }
  if (i == N) row_off[N] = E;
}

__global__ void k_fill(const int* __restrict__ src, const int* __restrict__ dst,
                       const int* __restrict__ row_off, int* __restrict__ cursor,
                       int* __restrict__ csr, int E) {
  int e = blockIdx.x * blockDim.x + threadIdx.x;
  if (e < E) {
    int d = dst[e];
    int p = atomicAdd(&cursor[d], 1);
    csr[row_off[d] + p] = src[e];
  }
}

// ---------------- per-layer kernels ----------------

// One wave per node; lane covers 2 consecutive features (float2 -> 512B/row coalesced).
__global__ __launch_bounds__(256) void k_aggregate(const float* __restrict__ X,
    const int* __restrict__ row_off, const int* __restrict__ csr,
    const float* __restrict__ inv_deg, float* __restrict__ agg, int N) {
  int wave = (int)((blockIdx.x * blockDim.x + threadIdx.x) >> 6);
  int lane = threadIdx.x & 63;
  if (wave >= N) return;
  int start = row_off[wave], end = row_off[wave + 1];
  float2 acc = make_float2(0.f, 0.f);
  for (int base = start; base < end; base += 64) {
    int n = min(64, end - base);
    int eid = (lane < n) ? csr[base + lane] : 0;
    for (int j = 0; j < n; ++j) {
      int s = __shfl(eid, j);
      const float2 v = *(const float2*)(X + (size_t)s * D + 2 * lane);
      acc.x += v.x;
      acc.y += v.y;
    }
  }
  float inv = inv_deg[wave];
  *(float2*)(agg + (size_t)wave * D + 2 * lane) = make_float2(acc.x * inv, acc.y * inv);
}

// Fused out = ELU(agg @ Wrel + b + Xin @ Wroot). 32-row tile in LDS.
// Thread = (col c, row-half g) -> 16 outputs. Safe for Xout==agg or Xout==Xin
// (each block only writes rows it staged into LDS before the barrier).
__global__ __launch_bounds__(256) void k_layer(const float* __restrict__ agg,
    const float* __restrict__ Xin, const float* __restrict__ Wrel,
    const float* __restrict__ brel, const float* __restrict__ Wroot,
    float* __restrict__ Xout, int N) {
  __shared__ float sA[32][D];
  __shared__ float sX[32][D];
  int tid = threadIdx.x;
  int r0 = blockIdx.x * 32;
  for (int i = tid; i < 32 * 32; i += 256) { // float4 granules
    int r = i >> 5, c4 = i & 31;
    int row = r0 + r;
    float4 va = make_float4(0.f, 0.f, 0.f, 0.f), vx = va;
    if (row < N) {
      va = ((const float4*)(agg + (size_t)row * D))[c4];
      vx = ((const float4*)(Xin + (size_t)row * D))[c4];
    }
    ((float4*)sA[r])[c4] = va;
    ((float4*)sX[r])[c4] = vx;
  }
  __syncthreads();

  int c = tid & 127;
  int g = tid >> 7;
  int rb = g * 16;
  float acc[16];
  float bias = brel[c];
#pragma unroll
  for (int r = 0; r < 16; ++r) acc[r] = bias;

  const float* wr = Wrel + c;
#pragma unroll 2
  for (int k4 = 0; k4 < 32; ++k4) {
    float w0 = wr[(k4 * 4 + 0) * D];
    float w1 = wr[(k4 * 4 + 1) * D];
    float w2 = wr[(k4 * 4 + 2) * D];
    float w3 = wr[(k4 * 4 + 3) * D];
#pragma unroll
    for (int r = 0; r < 16; ++r) {
      float4 a = ((const float4*)sA[rb + r])[k4];
      acc[r] += a.x * w0 + a.y * w1 + a.z * w2 + a.w * w3;
    }
  }
  const float* wo = Wroot + c;
#pragma unroll 2
  for (int k4 = 0; k4 < 32; ++k4) {
    float w0 = wo[(k4 * 4 + 0) * D];
    float w1 = wo[(k4 * 4 + 1) * D];
    float w2 = wo[(k4 * 4 + 2) * D];
    float w3 = wo[(k4 * 4 + 3) * D];
#pragma unroll
    for (int r = 0; r < 16; ++r) {
      float4 a = ((const float4*)sX[rb + r])[k4];
      acc[r] += a.x * w0 + a.y * w1 + a.z * w2 + a.w * w3;
    }
  }

#pragma unroll
  for (int r = 0; r < 16; ++r) {
    int row = r0 + rb + r;
    if (row < N) {
      float v = acc[r];
      Xout[(size_t)row * D + c] = v > 0.f ? v : expm1f(v);
    }
  }
}

// ---------------- launch ----------------

extern "C" void kernel_launch(void* const* d_in, const int* in_sizes, int n_in,
                              void* d_out, int out_size, void* d_ws, size_t ws_size,
                              hipStream_t stream) {
  const float* X0    = (const float*)d_in[0];
  const int*   eidx  = (const int*)d_in[1];
  const float* Wrel  = (const float*)d_in[2];
  const float* brel  = (const float*)d_in[3];
  const float* Wroot = (const float*)d_in[4];
  float* out = (float*)d_out;

  const int N = in_sizes[0] / D;
  const int E = in_sizes[1] / 2;
  const int L = in_sizes[3] / D;
  const int* src = eidx;      // edge_index[0]
  const int* dst = eidx + E;  // edge_index[1]

  char* ws = (char*)d_ws;
  size_t off = 0;
  auto carve = [&](size_t bytes) -> void* {
    void* p = ws + off;
    off = (off + bytes + 255) & ~(size_t)255;
    return p;
  };
  float* xbuf    = (float*)carve((size_t)N * D * sizeof(float));
  int*   deg     = (int*)carve((size_t)N * sizeof(int));
  int*   row_off = (int*)carve((size_t)(N + 1) * sizeof(int));
  int*   cursor  = (int*)carve((size_t)N * sizeof(int));
  int*   csr     = (int*)carve((size_t)E * sizeof(int));
  float* inv_deg = (float*)carve((size_t)N * sizeof(float));
  const int NB = (N + 255) / 256;
  int*   partials = (int*)carve((size_t)NB * sizeof(int));
  (void)ws_size; (void)n_in; (void)out_size;

  hipMemsetAsync(deg, 0, (size_t)N * sizeof(int), stream);
  hipMemsetAsync(cursor, 0, (size_t)N * sizeof(int), stream);

  const int eb = (E + 255) / 256;
  k_count<<<eb, 256, 0, stream>>>(dst, deg, E);
  k_scan_intra<<<NB, 256, 0, stream>>>(deg, row_off, partials, N);
  k_scan_partials<<<1, 256, 0, stream>>>(partials, NB);
  k_finalize<<<NB, 256, 0, stream>>>(row_off, partials, deg, inv_deg, N, E);
  k_fill<<<eb, 256, 0, stream>>>(src, dst, row_off, cursor, csr, E);

  // Layer chain with minimal buffers:
  //  agg buffer alternates d_out / xbuf; epilogue is row-tile in-place safe.
  const float* Xin = X0;
  for (int l = 0; l < L; ++l) {
    float* a = (l & 1) ? xbuf : out;
    k_aggregate<<<(N + 3) / 4, 256, 0, stream>>>(Xin, row_off, csr, inv_deg, a, N);
    float* Xout = (l == L - 1) ? out : a;
    k_layer<<<(N + 31) / 32, 256, 0, stream>>>(a, Xin, Wrel + (size_t)l * D * D,
        brel + (size_t)l * D, Wroot + (size_t)l * D * D, Xout, N);
    Xin = Xout;
  }
}